// Round 17
// baseline (233.605 us; speedup 1.0000x reference)
//
#include <hip/hip_runtime.h>
#include <math.h>

#define E_ 8
#define T_ 4096
#define K_ 2048
#define I_ 768
#define TWOI 1536
#define NPAIR (2*T_)

typedef unsigned short u16;
typedef signed char i8;
typedef __attribute__((ext_vector_type(8))) __bf16 bf16x8;
typedef __attribute__((ext_vector_type(4))) float f32x4;
typedef __attribute__((ext_vector_type(4))) int i32x4;
typedef __attribute__((ext_vector_type(4))) unsigned u32x4;
typedef __attribute__((ext_vector_type(8))) u16 u16x8;
typedef __attribute__((ext_vector_type(4))) u16 u16x4;
typedef __attribute__((ext_vector_type(4))) int int4v;
typedef __attribute__((ext_vector_type(4))) float float4v;

typedef __attribute__((address_space(3))) char lds_c;
typedef __attribute__((address_space(1))) const char g_c;

__device__ inline void gld16(const void* g, void* l) {
    __builtin_amdgcn_global_load_lds((g_c*)g, (lds_c*)l, 16, 0, 0);
}

__device__ inline u16 f2bf(float x) {
    unsigned u = __builtin_bit_cast(unsigned, x);
    unsigned r = 0x7fffu + ((u >> 16) & 1u);
    u += r;
    return (u16)(u >> 16);
}
__device__ inline float bf2f(u16 b) {
    unsigned u = ((unsigned)b) << 16;
    return __builtin_bit_cast(float, u);
}
__device__ inline unsigned pack4(int4v q) {
    return (unsigned)((unsigned char)(char)(q[0] - 1))
         | ((unsigned)((unsigned char)(char)(q[1] - 1)) << 8)
         | ((unsigned)((unsigned char)(char)(q[2] - 1)) << 16)
         | ((unsigned)((unsigned char)(char)(q[3] - 1)) << 24);
}

// ---------------- fused streaming: zero(out) + cvt13 + wave-per-token qx ----------------
#define NBLK 2048
__global__ __launch_bounds__(256) void k_fusedA(
    const int* __restrict__ w13q, const float* __restrict__ logits,
    const float* __restrict__ x, const float* __restrict__ alpha13,
    i8* __restrict__ wc13, float* __restrict__ outz,
    i8* __restrict__ xq, float* __restrict__ sx,
    int* __restrict__ tid2, float* __restrict__ tw, int* __restrict__ cursors)
{
    int tid = threadIdx.x;
    int bid = blockIdx.x;
    if (bid == 0 && tid < E_) cursors[tid] = 0;

    // phase Z: zero out (T*K = 8388608 floats; 16 per thread over 524288 threads)
    {
        long u0 = ((long)bid * 256 + tid) * 16;
        f32x4 z = (f32x4){0.f, 0.f, 0.f, 0.f};
        *(f32x4*)(outz + u0)      = z;
        *(f32x4*)(outz + u0 + 4)  = z;
        *(f32x4*)(outz + u0 + 8)  = z;
        *(f32x4*)(outz + u0 + 12) = z;
    }
    // phase A: w13 int32 codes -> i8 (grid-stride, 12 iters, nt loads)
    {
        const int4v* src = (const int4v*)w13q;
        unsigned* dst = (unsigned*)wc13;
        const long n = 6291456;           // 25165824 / 4
        const long stride = (long)NBLK * 256;
#pragma unroll 2
        for (long u = (long)bid * 256 + tid; u < n; u += stride) {
            int4v q = __builtin_nontemporal_load(src + u);
            dst[u] = pack4(q);
        }
    }
    // phase C: wave-per-token routing + i8 quantization of BOTH pairs (x read once)
    {
        int wv = bid * 4 + (tid >> 6);
        if (wv < T_) {
            int lane = tid & 63;
            int t = wv;
            float l[E_];
#pragma unroll
            for (int e = 0; e < E_; ++e) l[e] = logits[t * E_ + e];
            int e0 = 0; float mx0 = l[0];
#pragma unroll
            for (int e = 1; e < E_; ++e) if (l[e] > mx0) { mx0 = l[e]; e0 = e; }
            int e1 = -1; float mx1 = -1e30f;
#pragma unroll
            for (int e = 0; e < E_; ++e) if (e != e0 && l[e] > mx1) { mx1 = l[e]; e1 = e; }

            float4v xr[8];
#pragma unroll
            for (int c = 0; c < 8; ++c)
                xr[c] = *(const float4v*)(x + (long)t * K_ + c * 256 + lane * 4);

#pragma unroll
            for (int s = 0; s < 2; ++s) {
                int e = s ? e1 : e0;
                int p = 2 * t + s;
                float4v xa[8];
                float m = 0.f;
#pragma unroll
                for (int c = 0; c < 8; ++c) {
                    float4v a = *(const float4v*)(alpha13 + (long)e * K_ + c * 256 + lane * 4);
                    xa[c] = xr[c] * a;
#pragma unroll
                    for (int j = 0; j < 4; ++j) m = fmaxf(m, fabsf(xa[c][j]));
                }
#pragma unroll
                for (int off = 32; off >= 1; off >>= 1) m = fmaxf(m, __shfl_xor(m, off));
                float inv = (m > 0.f) ? 127.0f / m : 0.f;
#pragma unroll
                for (int c = 0; c < 8; ++c) {
                    unsigned pk = 0;
#pragma unroll
                    for (int j = 0; j < 4; ++j) {
                        int qv = __float2int_rn(xa[c][j] * inv);
                        pk |= ((unsigned)(unsigned char)(char)qv) << (8 * j);
                    }
                    *(unsigned*)(xq + (long)p * K_ + c * 256 + lane * 4) = pk;
                }
                if (lane == 0) sx[p] = m / 127.0f;
            }
            if (lane == 0) {
                tid2[2 * t + 0] = e0; tid2[2 * t + 1] = e1;
                float w0 = 1.0f / (1.0f + expf(mx1 - mx0));
                tw[2 * t + 0] = w0; tw[2 * t + 1] = 1.0f - w0;
            }
        }
    }
}

// ---------------- lists2: redundant histogram + offsets + pairTok (one dispatch) ----------------
__global__ __launch_bounds__(256) void k_lists2(
    const int* __restrict__ tid2, int* __restrict__ offsets,
    int* __restrict__ cursors, int* __restrict__ pairTok)
{
    int tid = threadIdx.x;
    int c[E_];
#pragma unroll
    for (int e = 0; e < E_; ++e) c[e] = 0;
    for (int j = 0; j < 32; ++j) {
        int v = tid2[tid * 32 + j];
#pragma unroll
        for (int e = 0; e < E_; ++e) c[e] += (v == e) ? 1 : 0;
    }
#pragma unroll
    for (int e = 0; e < E_; ++e)
#pragma unroll
        for (int off = 32; off >= 1; off >>= 1)
            c[e] += __shfl_xor(c[e], off);
    __shared__ int ws[4][E_];
    __shared__ int offs[E_ + 1];
    if ((tid & 63) == 0)
#pragma unroll
        for (int e = 0; e < E_; ++e) ws[tid >> 6][e] = c[e];
    __syncthreads();
    if (tid == 0) {
        int s2 = 0;
        for (int e = 0; e < E_; ++e) {
            int ce = ws[0][e] + ws[1][e] + ws[2][e] + ws[3][e];
            offs[e] = s2; s2 += ce;
        }
        offs[E_] = s2;
        if (blockIdx.x == 0)
            for (int e = 0; e <= E_; ++e) offsets[e] = offs[e];
    }
    __syncthreads();
    int t = blockIdx.x * 256 + tid;
#pragma unroll
    for (int s = 0; s < 2; ++s) {
        int e = tid2[t * 2 + s];
        int pos = atomicAdd(&cursors[e], 1);
        pairTok[offs[e] + pos] = (t << 1) | s;
    }
}

// ---------------- GEMM1: i8 256x256 2-phase + fused silu*u; extra blocks do w2 cvt ----------------
#define G1GRID (8 * (T_ / 256) * 6)   // 768
#define CVT2BLK 256
__global__ __launch_bounds__(512, 2) void k_g1i8(
    const i8* __restrict__ A,       // xq [NPAIR][K] pair-id order
    const i8* __restrict__ B,       // wc13 codes [E][2I][K]
    const int* __restrict__ pairTok, const int* __restrict__ offsets,
    const float* __restrict__ sx,   // [NPAIR] pair-id order
    u16* __restrict__ C,            // ab [NPAIR][I] list order = silu(g)*u
    const int* __restrict__ w2q, const float* __restrict__ alpha2,
    u16* __restrict__ wb2)          // w2 bf16 (alpha2 folded) - produced here
{
    int bid = blockIdx.x;
    if (bid >= G1GRID) {
        // w2 conversion: grid-stride over 3145728 int4v units
        int cb = bid - G1GRID;
        const int4v* src = (const int4v*)w2q;
        const long n = 3145728;
        const long stride = (long)CVT2BLK * 512;
        for (long u = (long)cb * 512 + threadIdx.x; u < n; u += stride) {
            long g = u * 4;
            int i = (int)(g % I_);
            int e = (int)(g / ((long)K_ * I_));
            int4v q = __builtin_nontemporal_load(src + u);
            float4v a = *(const float4v*)(alpha2 + e * I_ + i);
            u16x4 r;
            r[0] = f2bf((float)(q[0] - 1) * a[0]);
            r[1] = f2bf((float)(q[1] - 1) * a[1]);
            r[2] = f2bf((float)(q[2] - 1) * a[2]);
            r[3] = f2bf((float)(q[3] - 1) * a[3]);
            *(u16x4*)(wb2 + g) = r;
        }
        return;
    }

    int e  = bid & 7;
    int r_ = bid >> 3;
    int mc = r_ / 6;
    int nch = r_ % 6;
    int base = offsets[e];
    int cnt  = offsets[e + 1] - base;
    int m0 = mc * 256;
    if (m0 >= cnt) return;
    int n0 = nch * 128;

    __shared__ __attribute__((aligned(16))) i8 SHM[131072];
    i8* As = SHM;
    i8* Bs = SHM + 65536;

    int tid = threadIdx.x;
    int lane = tid & 63;
    int wid = tid >> 6;
    int wr = wid >> 2, wc = wid & 3;
    int l15 = lane & 15;

    const i8* srcA[4];
    const i8* srcB[4];
#pragma unroll
    for (int j = 0; j < 4; ++j) {
        int chunk = j * 512 + tid;
        int row = chunk >> 3, ch = chunk & 7;
        int colsw = (ch ^ (row & 7)) * 16;
        int ra = m0 + row; if (ra >= cnt) ra = cnt - 1;
        srcA[j] = A + (long)pairTok[base + ra] * K_ + colsw;
        int grow = e * TWOI + (row >> 7) * I_ + n0 + (row & 127);
        srcB[j] = B + (long)grow * K_ + colsw;
    }

    auto stage = [&](int bs, int t) {
        int k0 = t * 128;
        i8* dA = As + bs * 32768;
        i8* dB = Bs + bs * 32768;
#pragma unroll
        for (int j = 0; j < 4; ++j) {
            gld16(srcA[j] + k0, dA + j * 8192 + tid * 16);
            gld16(srcB[j] + k0, dB + j * 8192 + tid * 16);
        }
    };

    int kq16 = ((lane >> 4) & 3) * 16;

    i32x4 a[4][2], b[4][2];
    i32x4 acc[8][4];
#pragma unroll
    for (int mf = 0; mf < 8; ++mf)
#pragma unroll
        for (int nf = 0; nf < 4; ++nf)
            acc[mf][nf] = (i32x4){0, 0, 0, 0};

    auto rdA = [&](int bs, int h64) {
#pragma unroll
        for (int mf = 0; mf < 4; ++mf) {
            int row = wr * 128 + h64 + mf * 16 + l15;
            const i8* p = As + bs * 32768 + row * 128;
            int xr = (row & 7) << 4;
            a[mf][0] = *(const i32x4*)(p + ((kq16) ^ xr));
            a[mf][1] = *(const i32x4*)(p + ((64 + kq16) ^ xr));
        }
    };
    auto rdB = [&](int bs) {
#pragma unroll
        for (int nf = 0; nf < 4; ++nf) {
            int row = wc * 64 + nf * 16 + l15;
            const i8* p = Bs + bs * 32768 + row * 128;
            int xr = (row & 7) << 4;
            b[nf][0] = *(const i32x4*)(p + ((kq16) ^ xr));
            b[nf][1] = *(const i32x4*)(p + ((64 + kq16) ^ xr));
        }
    };
    auto mm = [&](int mh) {
#pragma unroll
        for (int ks = 0; ks < 2; ++ks)
#pragma unroll
            for (int mf = 0; mf < 4; ++mf)
#pragma unroll
                for (int nf = 0; nf < 4; ++nf)
                    acc[mh * 4 + mf][nf] = __builtin_amdgcn_mfma_i32_16x16x64_i8(
                        a[mf][ks], b[nf][ks], acc[mh * 4 + mf][nf], 0, 0, 0);
    };
    auto compute = [&](int bs) {
        rdB(bs);
        rdA(bs, 0);
        mm(0);
        rdA(bs, 64);
        mm(1);
    };

    stage(0, 0);
    __syncthreads();
#pragma unroll 1
    for (int t = 0; t < 16; t += 2) {
        stage(1, t + 1);
        compute(0);
        __syncthreads();
        if (t + 2 < 16) stage(0, t + 2);
        compute(1);
        __syncthreads();
    }

    u16* flat = (u16*)SHM;  // 131072 B = [256][256] u16
#pragma unroll
    for (int mf = 0; mf < 8; ++mf)
#pragma unroll
        for (int nf = 0; nf < 4; ++nf)
#pragma unroll
            for (int rg = 0; rg < 4; ++rg) {
                int row = wr * 128 + mf * 16 + (lane >> 4) * 4 + rg;
                int col = wc * 64 + nf * 16 + l15;
                flat[row * 256 + (col ^ ((row & 7) << 3))] = f2bf((float)acc[mf][nf][rg]);
            }
    __syncthreads();
    int row = tid >> 1;
    if (m0 + row < cnt) {
        float s = sx[pairTok[base + m0 + row]];
        int xr = (row & 7) << 3;
        int half = tid & 1;
        u16* dst = C + (long)(base + m0 + row) * I_ + n0 + half * 64;
#pragma unroll
        for (int jj = 0; jj < 8; ++jj) {
            u16x8 gv = *(const u16x8*)&flat[row * 256 + ((half * 64 + jj * 8) ^ xr)];
            u16x8 uv = *(const u16x8*)&flat[row * 256 + ((128 + half * 64 + jj * 8) ^ xr)];
            u16x8 r;
#pragma unroll
            for (int q = 0; q < 8; ++q) {
                float g = bf2f(gv[q]) * s, u = bf2f(uv[q]) * s;
                r[q] = f2bf(g / (1.0f + expf(-g)) * u);
            }
            *(u16x8*)(dst + jj * 8) = r;
        }
    }
}

// ---------------- GEMM2: bf16 256x256 2-phase, fused weighted-combine via atomics ----------------
__global__ __launch_bounds__(512, 2) void k_g2(
    const u16* __restrict__ A,      // ab [NPAIR][I] bf16, list order
    const u16* __restrict__ B,      // wb2 [E][K][I] bf16 (alpha2 folded)
    const int* __restrict__ pairTok, const int* __restrict__ offsets,
    const float* __restrict__ tw,   // [NPAIR] routing weights (pair-id order)
    float* __restrict__ out)        // [T][K] f32, pre-zeroed; += tw * y
{
    int bid = blockIdx.x;
    int e  = bid & 7;
    int r_ = bid >> 3;
    int mc = r_ >> 3;
    int nch = r_ & 7;
    int base = offsets[e];
    int cnt  = offsets[e + 1] - base;
    int m0 = mc * 256;
    if (m0 >= cnt) return;
    int n0 = nch * 256;

    __shared__ __attribute__((aligned(16))) char SHM[131072];
    __shared__ float rowW[256];
    __shared__ int   rowT[256];
    u16* ldsA = (u16*)SHM;               // [2][256][64] u16 = 64 KB
    u16* ldsB = (u16*)(SHM + 65536);     // [2][256][64] u16 = 64 KB

    int tid = threadIdx.x;
    int lane = tid & 63;
    int wid = tid >> 6;
    int wr = wid >> 2, wc = wid & 3;
    int l15 = lane & 15;

    const u16* srcA[2][2];
    const u16* srcB[2][2];
#pragma unroll
    for (int h = 0; h < 2; ++h)
#pragma unroll
        for (int j = 0; j < 2; ++j) {
            int slot = j * 512 + tid;
            int row = slot >> 3, ch = slot & 7;
            int colsw = (ch ^ (row & 7)) * 8;
            int ra = m0 + h * 128 + row;
            if (ra >= cnt) ra = cnt - 1;
            srcA[h][j] = A + (long)(base + ra) * I_ + colsw;
            long brow = (long)e * K_ + n0 + h * 128 + row;
            srcB[h][j] = B + brow * (long)I_ + colsw;
        }
    int d0 = tid * 8, d1 = (512 + tid) * 8;

    auto stage = [&](int bs, int t) {
        int k0 = t * 64;
        u16* dA = ldsA + bs * 16384;
        u16* dB = ldsB + bs * 16384;
#pragma unroll
        for (int h = 0; h < 2; ++h) {
            gld16(srcA[h][0] + k0, dA + h * 8192 + d0);
            gld16(srcA[h][1] + k0, dA + h * 8192 + d1);
            gld16(srcB[h][0] + k0, dB + h * 8192 + d0);
            gld16(srcB[h][1] + k0, dB + h * 8192 + d1);
        }
    };

    int kc0 = ((((lane >> 4) & 3) * 8)) ^ ((lane & 7) * 8);
    int kc1 = (32 + (((lane >> 4) & 3) * 8)) ^ ((lane & 7) * 8);

    bf16x8 a[4][2], b[4][2];
    f32x4 acc[8][4];
#pragma unroll
    for (int mf = 0; mf < 8; ++mf)
#pragma unroll
        for (int nf = 0; nf < 4; ++nf)
            acc[mf][nf] = (f32x4){0.f, 0.f, 0.f, 0.f};

    auto rdA = [&](int bs, int h64) {
#pragma unroll
        for (int mf = 0; mf < 4; ++mf) {
            const u16* p = ldsA + bs * 16384 + (wr * 128 + h64 + mf * 16 + l15) * 64;
            a[mf][0] = __builtin_bit_cast(bf16x8, *(const u16x8*)(p + kc0));
            a[mf][1] = __builtin_bit_cast(bf16x8, *(const u16x8*)(p + kc1));
        }
    };
    auto rdB = [&](int bs) {
#pragma unroll
        for (int nf = 0; nf < 4; ++nf) {
            const u16* p = ldsB + bs * 16384 + (wc * 64 + nf * 16 + l15) * 64;
            b[nf][0] = __builtin_bit_cast(bf16x8, *(const u16x8*)(p + kc0));
            b[nf][1] = __builtin_bit_cast(bf16x8, *(const u16x8*)(p + kc1));
        }
    };
    auto mm = [&](int mh) {
#pragma unroll
        for (int ks = 0; ks < 2; ++ks)
#pragma unroll
            for (int mf = 0; mf < 4; ++mf)
#pragma unroll
                for (int nf = 0; nf < 4; ++nf)
                    acc[mh * 4 + mf][nf] = __builtin_amdgcn_mfma_f32_16x16x32_bf16(
                        a[mf][ks], b[nf][ks], acc[mh * 4 + mf][nf], 0, 0, 0);
    };
    auto compute = [&](int bs) {
        rdB(bs);
        rdA(bs, 0);
        mm(0);
        rdA(bs, 64);
        mm(1);
    };

    // NT = 12 (K-dim = I_ = 768, BK = 64)
    stage(0, 0);
    __syncthreads();
#pragma unroll 1
    for (int t = 0; t < 12; t += 2) {
        stage(1, t + 1);
        compute(0);
        __syncthreads();
        if (t + 2 < 12) stage(0, t + 2);
        compute(1);
        __syncthreads();
    }

    u16* flat = (u16*)SHM;  // 131072 B = [256][256] u16
#pragma unroll
    for (int mf = 0; mf < 8; ++mf)
#pragma unroll
        for (int nf = 0; nf < 4; ++nf)
#pragma unroll
            for (int rg = 0; rg < 4; ++rg) {
                int row = wr * 128 + mf * 16 + (lane >> 4) * 4 + rg;
                int col = wc * 64 + nf * 16 + l15;
                flat[row * 256 + (col ^ ((row & 7) << 3))] = f2bf(acc[mf][nf][rg]);
            }
    if (tid < 256) {
        int row = tid;
        if (m0 + row < cnt) {
            int pt = pairTok[base + m0 + row];
            rowW[row] = tw[pt];
            rowT[row] = pt >> 1;
        } else {
            rowW[row] = 0.f;
            rowT[row] = -1;
        }
    }
    __syncthreads();
    int nvalid = cnt - m0; if (nvalid > 256) nvalid = 256;
#pragma unroll 4
    for (int j = 0; j < 128; ++j) {
        int idx = j * 512 + tid;
        int row = idx >> 8;
        if (row >= nvalid) break;
        int col = idx & 255;
        float v = bf2f(flat[row * 256 + (col ^ ((row & 7) << 3))]) * rowW[row];
        atomicAdd(&out[(long)rowT[row] * K_ + n0 + col], v);
    }
}

// ---------------- launch ----------------
extern "C" void kernel_launch(void* const* d_in, const int* in_sizes, int n_in,
                              void* d_out, int out_size, void* d_ws, size_t ws_size,
                              hipStream_t stream) {
    const float* x       = (const float*)d_in[0];
    const float* logits  = (const float*)d_in[1];
    const int*   w13q    = (const int*)d_in[2];
    const int*   w2q     = (const int*)d_in[3];
    const float* alpha13 = (const float*)d_in[4];
    const float* alpha2  = (const float*)d_in[5];
    float* out = (float*)d_out;

    char* ws = (char*)d_ws;
    i8*  wc13 = (i8*)(ws);                          // 25165824 B (codes i8)
    u16* wb2  = (u16*)(ws + 50331648);              // 25165824 B (bf16, alpha2 folded)
    i8*  xq   = (i8*)(ws + 75497472);               // 16777216 B (pair-id order)
    u16* ab   = (u16*)(ws + 92274688);              // 12582912 B (silu*u bf16, list order)
    int* pairTok = (int*)(ws + 138412032);          // 8192 ints
    int* tid2    = pairTok + NPAIR;                 // 8192 ints
    float* tw    = (float*)(tid2 + NPAIR);          // 8192 floats
    int* counts  = (int*)(tw + NPAIR);              // 8 (unused)
    int* offsets = counts + 8;                      // 9
    int* cursors = offsets + 9;                     // 8
    float* sx    = (float*)(cursors + 8);           // 8192 floats (pair-id order)

    // fused streaming: out-zero + w13 conversion + routing + per-pair quantization
    k_fusedA<<<NBLK, 256, 0, stream>>>(
        w13q, logits, x, alpha13, wc13, out, xq, sx, tid2, tw, cursors);

    // histogram + offsets + per-expert token lists (single dispatch)
    k_lists2<<<T_ / 256, 256, 0, stream>>>(tid2, offsets, cursors, pairTok);

    // GEMM1 i8 + fused silu*u -> ab; extra blocks convert w2 -> wb2 concurrently
    k_g1i8<<<G1GRID + CVT2BLK, 512, 0, stream>>>(
        xq, wc13, pairTok, offsets, sx, ab, w2q, alpha2, wb2);

    // GEMM2 bf16 (M x 2048 x 768) + fused weighted combine -> out (atomicAdd f32)
    k_g2<<<8 * (T_ / 256) * (K_ / 256), 512, 0, stream>>>(ab, wb2, pairTok, offsets, tw, out);
}

// Round 18
// 199.217 us; speedup vs baseline: 1.1726x; 1.1726x over previous
//
#include <hip/hip_runtime.h>
#include <math.h>

#define E_ 8
#define T_ 4096
#define K_ 2048
#define I_ 768
#define TWOI 1536
#define NPAIR (2*T_)

typedef unsigned short u16;
typedef signed char i8;
typedef __attribute__((ext_vector_type(8))) __bf16 bf16x8;
typedef __attribute__((ext_vector_type(4))) float f32x4;
typedef __attribute__((ext_vector_type(4))) int i32x4;
typedef __attribute__((ext_vector_type(8))) u16 u16x8;
typedef __attribute__((ext_vector_type(4))) u16 u16x4;
typedef __attribute__((ext_vector_type(4))) int int4v;
typedef __attribute__((ext_vector_type(4))) float float4v;

typedef __attribute__((address_space(3))) char lds_c;
typedef __attribute__((address_space(1))) const char g_c;

__device__ inline void gld16(const void* g, void* l) {
    __builtin_amdgcn_global_load_lds((g_c*)g, (lds_c*)l, 16, 0, 0);
}

__device__ inline u16 f2bf(float x) {
    unsigned u = __builtin_bit_cast(unsigned, x);
    unsigned r = 0x7fffu + ((u >> 16) & 1u);
    u += r;
    return (u16)(u >> 16);
}
__device__ inline float bf2f(u16 b) {
    unsigned u = ((unsigned)b) << 16;
    return __builtin_bit_cast(float, u);
}
__device__ inline unsigned pack4(int4v q) {
    return (unsigned)((unsigned char)(char)(q[0] - 1))
         | ((unsigned)((unsigned char)(char)(q[1] - 1)) << 8)
         | ((unsigned)((unsigned char)(char)(q[2] - 1)) << 16)
         | ((unsigned)((unsigned char)(char)(q[3] - 1)) << 24);
}

// ---------------- fused streaming: cvt13 + wave-per-token qx ----------------
#define NBLK 2048
__global__ __launch_bounds__(256) void k_fusedA(
    const int* __restrict__ w13q, const float* __restrict__ logits,
    const float* __restrict__ x, const float* __restrict__ alpha13,
    i8* __restrict__ wc13,
    i8* __restrict__ xq, float* __restrict__ sx,
    int* __restrict__ tid2, float* __restrict__ tw, int* __restrict__ cursors)
{
    int tid = threadIdx.x;
    int bid = blockIdx.x;
    if (bid == 0 && tid < E_) cursors[tid] = 0;

    // phase A: w13 int32 codes -> i8 (grid-stride, 12 iters, nt loads)
    {
        const int4v* src = (const int4v*)w13q;
        unsigned* dst = (unsigned*)wc13;
        const long n = 6291456;           // 25165824 / 4
        const long stride = (long)NBLK * 256;
#pragma unroll 2
        for (long u = (long)bid * 256 + tid; u < n; u += stride) {
            int4v q = __builtin_nontemporal_load(src + u);
            dst[u] = pack4(q);
        }
    }
    // phase C: wave-per-token routing + i8 quantization of BOTH pairs (x read once)
    {
        int wv = bid * 4 + (tid >> 6);
        if (wv < T_) {
            int lane = tid & 63;
            int t = wv;
            float l[E_];
#pragma unroll
            for (int e = 0; e < E_; ++e) l[e] = logits[t * E_ + e];
            int e0 = 0; float mx0 = l[0];
#pragma unroll
            for (int e = 1; e < E_; ++e) if (l[e] > mx0) { mx0 = l[e]; e0 = e; }
            int e1 = -1; float mx1 = -1e30f;
#pragma unroll
            for (int e = 0; e < E_; ++e) if (e != e0 && l[e] > mx1) { mx1 = l[e]; e1 = e; }

            float4v xr[8];
#pragma unroll
            for (int c = 0; c < 8; ++c)
                xr[c] = *(const float4v*)(x + (long)t * K_ + c * 256 + lane * 4);

#pragma unroll
            for (int s = 0; s < 2; ++s) {
                int e = s ? e1 : e0;
                int p = 2 * t + s;
                float4v xa[8];
                float m = 0.f;
#pragma unroll
                for (int c = 0; c < 8; ++c) {
                    float4v a = *(const float4v*)(alpha13 + (long)e * K_ + c * 256 + lane * 4);
                    xa[c] = xr[c] * a;
#pragma unroll
                    for (int j = 0; j < 4; ++j) m = fmaxf(m, fabsf(xa[c][j]));
                }
#pragma unroll
                for (int off = 32; off >= 1; off >>= 1) m = fmaxf(m, __shfl_xor(m, off));
                float inv = (m > 0.f) ? 127.0f / m : 0.f;
#pragma unroll
                for (int c = 0; c < 8; ++c) {
                    unsigned pk = 0;
#pragma unroll
                    for (int j = 0; j < 4; ++j) {
                        int qv = __float2int_rn(xa[c][j] * inv);
                        pk |= ((unsigned)(unsigned char)(char)qv) << (8 * j);
                    }
                    *(unsigned*)(xq + (long)p * K_ + c * 256 + lane * 4) = pk;
                }
                if (lane == 0) sx[p] = m / 127.0f;
            }
            if (lane == 0) {
                tid2[2 * t + 0] = e0; tid2[2 * t + 1] = e1;
                float w0 = 1.0f / (1.0f + expf(mx1 - mx0));
                tw[2 * t + 0] = w0; tw[2 * t + 1] = 1.0f - w0;
            }
        }
    }
}

// ---------------- lists2: redundant histogram + offsets + pairTok (one dispatch) ----------------
__global__ __launch_bounds__(256) void k_lists2(
    const int* __restrict__ tid2, int* __restrict__ offsets,
    int* __restrict__ cursors, int* __restrict__ pairTok)
{
    int tid = threadIdx.x;
    int c[E_];
#pragma unroll
    for (int e = 0; e < E_; ++e) c[e] = 0;
    for (int j = 0; j < 32; ++j) {
        int v = tid2[tid * 32 + j];
#pragma unroll
        for (int e = 0; e < E_; ++e) c[e] += (v == e) ? 1 : 0;
    }
#pragma unroll
    for (int e = 0; e < E_; ++e)
#pragma unroll
        for (int off = 32; off >= 1; off >>= 1)
            c[e] += __shfl_xor(c[e], off);
    __shared__ int ws[4][E_];
    __shared__ int offs[E_ + 1];
    if ((tid & 63) == 0)
#pragma unroll
        for (int e = 0; e < E_; ++e) ws[tid >> 6][e] = c[e];
    __syncthreads();
    if (tid == 0) {
        int s2 = 0;
        for (int e = 0; e < E_; ++e) {
            int ce = ws[0][e] + ws[1][e] + ws[2][e] + ws[3][e];
            offs[e] = s2; s2 += ce;
        }
        offs[E_] = s2;
        if (blockIdx.x == 0)
            for (int e = 0; e <= E_; ++e) offsets[e] = offs[e];
    }
    __syncthreads();
    int t = blockIdx.x * 256 + tid;
#pragma unroll
    for (int s = 0; s < 2; ++s) {
        int e = tid2[t * 2 + s];
        int pos = atomicAdd(&cursors[e], 1);
        pairTok[offs[e] + pos] = (t << 1) | s;
    }
}

// ---------------- GEMM1: i8 256x256 2-phase + fused silu*u; extra blocks do w2 cvt ----------------
#define G1GRID (8 * (T_ / 256) * 6)   // 768
#define CVT2BLK 256
__global__ __launch_bounds__(512, 2) void k_g1i8(
    const i8* __restrict__ A,       // xq [NPAIR][K] pair-id order
    const i8* __restrict__ B,       // wc13 codes [E][2I][K]
    const int* __restrict__ pairTok, const int* __restrict__ offsets,
    const float* __restrict__ sx,   // [NPAIR] pair-id order
    u16* __restrict__ C,            // ab [NPAIR][I] list order = silu(g)*u
    const int* __restrict__ w2q, const float* __restrict__ alpha2,
    u16* __restrict__ wb2)          // w2 bf16 (alpha2 folded) - produced here
{
    int bid = blockIdx.x;
    if (bid >= G1GRID) {
        // w2 conversion: grid-stride over 3145728 int4v units
        int cb = bid - G1GRID;
        const int4v* src = (const int4v*)w2q;
        const long n = 3145728;
        const long stride = (long)CVT2BLK * 512;
        for (long u = (long)cb * 512 + threadIdx.x; u < n; u += stride) {
            long g = u * 4;
            int i = (int)(g % I_);
            int e = (int)(g / ((long)K_ * I_));
            int4v q = __builtin_nontemporal_load(src + u);
            float4v a = *(const float4v*)(alpha2 + e * I_ + i);
            u16x4 r;
            r[0] = f2bf((float)(q[0] - 1) * a[0]);
            r[1] = f2bf((float)(q[1] - 1) * a[1]);
            r[2] = f2bf((float)(q[2] - 1) * a[2]);
            r[3] = f2bf((float)(q[3] - 1) * a[3]);
            *(u16x4*)(wb2 + g) = r;
        }
        return;
    }

    int e  = bid & 7;
    int r_ = bid >> 3;
    int mc = r_ / 6;
    int nch = r_ % 6;
    int base = offsets[e];
    int cnt  = offsets[e + 1] - base;
    int m0 = mc * 256;
    if (m0 >= cnt) return;
    int n0 = nch * 128;

    __shared__ __attribute__((aligned(16))) i8 SHM[131072];
    i8* As = SHM;
    i8* Bs = SHM + 65536;

    int tid = threadIdx.x;
    int lane = tid & 63;
    int wid = tid >> 6;
    int wr = wid >> 2, wc = wid & 3;
    int l15 = lane & 15;

    const i8* srcA[4];
    const i8* srcB[4];
#pragma unroll
    for (int j = 0; j < 4; ++j) {
        int chunk = j * 512 + tid;
        int row = chunk >> 3, ch = chunk & 7;
        int colsw = (ch ^ (row & 7)) * 16;
        int ra = m0 + row; if (ra >= cnt) ra = cnt - 1;
        srcA[j] = A + (long)pairTok[base + ra] * K_ + colsw;
        int grow = e * TWOI + (row >> 7) * I_ + n0 + (row & 127);
        srcB[j] = B + (long)grow * K_ + colsw;
    }

    auto stage = [&](int bs, int t) {
        int k0 = t * 128;
        i8* dA = As + bs * 32768;
        i8* dB = Bs + bs * 32768;
#pragma unroll
        for (int j = 0; j < 4; ++j) {
            gld16(srcA[j] + k0, dA + j * 8192 + tid * 16);
            gld16(srcB[j] + k0, dB + j * 8192 + tid * 16);
        }
    };

    int kq16 = ((lane >> 4) & 3) * 16;

    i32x4 a[4][2], b[4][2];
    i32x4 acc[8][4];
#pragma unroll
    for (int mf = 0; mf < 8; ++mf)
#pragma unroll
        for (int nf = 0; nf < 4; ++nf)
            acc[mf][nf] = (i32x4){0, 0, 0, 0};

    auto rdA = [&](int bs, int h64) {
#pragma unroll
        for (int mf = 0; mf < 4; ++mf) {
            int row = wr * 128 + h64 + mf * 16 + l15;
            const i8* p = As + bs * 32768 + row * 128;
            int xr = (row & 7) << 4;
            a[mf][0] = *(const i32x4*)(p + ((kq16) ^ xr));
            a[mf][1] = *(const i32x4*)(p + ((64 + kq16) ^ xr));
        }
    };
    auto rdB = [&](int bs) {
#pragma unroll
        for (int nf = 0; nf < 4; ++nf) {
            int row = wc * 64 + nf * 16 + l15;
            const i8* p = Bs + bs * 32768 + row * 128;
            int xr = (row & 7) << 4;
            b[nf][0] = *(const i32x4*)(p + ((kq16) ^ xr));
            b[nf][1] = *(const i32x4*)(p + ((64 + kq16) ^ xr));
        }
    };
    auto mm = [&](int mh) {
#pragma unroll
        for (int ks = 0; ks < 2; ++ks)
#pragma unroll
            for (int mf = 0; mf < 4; ++mf)
#pragma unroll
                for (int nf = 0; nf < 4; ++nf)
                    acc[mh * 4 + mf][nf] = __builtin_amdgcn_mfma_i32_16x16x64_i8(
                        a[mf][ks], b[nf][ks], acc[mh * 4 + mf][nf], 0, 0, 0);
    };
    auto compute = [&](int bs) {
        rdB(bs);
        rdA(bs, 0);
        mm(0);
        rdA(bs, 64);
        mm(1);
    };

    stage(0, 0);
    __syncthreads();
#pragma unroll 1
    for (int t = 0; t < 16; t += 2) {
        stage(1, t + 1);
        compute(0);
        __syncthreads();
        if (t + 2 < 16) stage(0, t + 2);
        compute(1);
        __syncthreads();
    }

    u16* flat = (u16*)SHM;  // 131072 B = [256][256] u16
#pragma unroll
    for (int mf = 0; mf < 8; ++mf)
#pragma unroll
        for (int nf = 0; nf < 4; ++nf)
#pragma unroll
            for (int rg = 0; rg < 4; ++rg) {
                int row = wr * 128 + mf * 16 + (lane >> 4) * 4 + rg;
                int col = wc * 64 + nf * 16 + l15;
                flat[row * 256 + (col ^ ((row & 7) << 3))] = f2bf((float)acc[mf][nf][rg]);
            }
    __syncthreads();
    int row = tid >> 1;
    if (m0 + row < cnt) {
        float s = sx[pairTok[base + m0 + row]];
        int xr = (row & 7) << 3;
        int half = tid & 1;
        u16* dst = C + (long)(base + m0 + row) * I_ + n0 + half * 64;
#pragma unroll
        for (int jj = 0; jj < 8; ++jj) {
            u16x8 gv = *(const u16x8*)&flat[row * 256 + ((half * 64 + jj * 8) ^ xr)];
            u16x8 uv = *(const u16x8*)&flat[row * 256 + ((128 + half * 64 + jj * 8) ^ xr)];
            u16x8 r;
#pragma unroll
            for (int q = 0; q < 8; ++q) {
                float g = bf2f(gv[q]) * s, u = bf2f(uv[q]) * s;
                r[q] = f2bf(g / (1.0f + expf(-g)) * u);
            }
            *(u16x8*)(dst + jj * 8) = r;
        }
    }
}

// ---------------- GEMM2: bf16 256x256 2-phase -> yb ----------------
__global__ __launch_bounds__(512, 2) void k_g2(
    const u16* __restrict__ A,      // ab [NPAIR][I] bf16, list order
    const u16* __restrict__ B,      // wb2 [E][K][I] bf16 (alpha2 folded)
    const int* __restrict__ pairTok, const int* __restrict__ offsets,
    u16* __restrict__ C)            // yb [NPAIR][K] scattered by pair
{
    int bid = blockIdx.x;
    int e  = bid & 7;
    int r_ = bid >> 3;
    int mc = r_ >> 3;
    int nch = r_ & 7;
    int base = offsets[e];
    int cnt  = offsets[e + 1] - base;
    int m0 = mc * 256;
    if (m0 >= cnt) return;
    int n0 = nch * 256;

    __shared__ __attribute__((aligned(16))) char SHM[131072];
    u16* ldsA = (u16*)SHM;               // [2][256][64] u16 = 64 KB
    u16* ldsB = (u16*)(SHM + 65536);     // [2][256][64] u16 = 64 KB

    int tid = threadIdx.x;
    int lane = tid & 63;
    int wid = tid >> 6;
    int wr = wid >> 2, wc = wid & 3;
    int l15 = lane & 15;

    const u16* srcA[2][2];
    const u16* srcB[2][2];
#pragma unroll
    for (int h = 0; h < 2; ++h)
#pragma unroll
        for (int j = 0; j < 2; ++j) {
            int slot = j * 512 + tid;
            int row = slot >> 3, ch = slot & 7;
            int colsw = (ch ^ (row & 7)) * 8;
            int ra = m0 + h * 128 + row;
            if (ra >= cnt) ra = cnt - 1;
            srcA[h][j] = A + (long)(base + ra) * I_ + colsw;
            long brow = (long)e * K_ + n0 + h * 128 + row;
            srcB[h][j] = B + brow * (long)I_ + colsw;
        }
    int d0 = tid * 8, d1 = (512 + tid) * 8;

    auto stage = [&](int bs, int t) {
        int k0 = t * 64;
        u16* dA = ldsA + bs * 16384;
        u16* dB = ldsB + bs * 16384;
#pragma unroll
        for (int h = 0; h < 2; ++h) {
            gld16(srcA[h][0] + k0, dA + h * 8192 + d0);
            gld16(srcA[h][1] + k0, dA + h * 8192 + d1);
            gld16(srcB[h][0] + k0, dB + h * 8192 + d0);
            gld16(srcB[h][1] + k0, dB + h * 8192 + d1);
        }
    };

    int kc0 = ((((lane >> 4) & 3) * 8)) ^ ((lane & 7) * 8);
    int kc1 = (32 + (((lane >> 4) & 3) * 8)) ^ ((lane & 7) * 8);

    bf16x8 a[4][2], b[4][2];
    f32x4 acc[8][4];
#pragma unroll
    for (int mf = 0; mf < 8; ++mf)
#pragma unroll
        for (int nf = 0; nf < 4; ++nf)
            acc[mf][nf] = (f32x4){0.f, 0.f, 0.f, 0.f};

    auto rdA = [&](int bs, int h64) {
#pragma unroll
        for (int mf = 0; mf < 4; ++mf) {
            const u16* p = ldsA + bs * 16384 + (wr * 128 + h64 + mf * 16 + l15) * 64;
            a[mf][0] = __builtin_bit_cast(bf16x8, *(const u16x8*)(p + kc0));
            a[mf][1] = __builtin_bit_cast(bf16x8, *(const u16x8*)(p + kc1));
        }
    };
    auto rdB = [&](int bs) {
#pragma unroll
        for (int nf = 0; nf < 4; ++nf) {
            const u16* p = ldsB + bs * 16384 + (wc * 64 + nf * 16 + l15) * 64;
            b[nf][0] = __builtin_bit_cast(bf16x8, *(const u16x8*)(p + kc0));
            b[nf][1] = __builtin_bit_cast(bf16x8, *(const u16x8*)(p + kc1));
        }
    };
    auto mm = [&](int mh) {
#pragma unroll
        for (int ks = 0; ks < 2; ++ks)
#pragma unroll
            for (int mf = 0; mf < 4; ++mf)
#pragma unroll
                for (int nf = 0; nf < 4; ++nf)
                    acc[mh * 4 + mf][nf] = __builtin_amdgcn_mfma_f32_16x16x32_bf16(
                        a[mf][ks], b[nf][ks], acc[mh * 4 + mf][nf], 0, 0, 0);
    };
    auto compute = [&](int bs) {
        rdB(bs);
        rdA(bs, 0);
        mm(0);
        rdA(bs, 64);
        mm(1);
    };

    // NT = 12 (K-dim = I_ = 768, BK = 64)
    stage(0, 0);
    __syncthreads();
#pragma unroll 1
    for (int t = 0; t < 12; t += 2) {
        stage(1, t + 1);
        compute(0);
        __syncthreads();
        if (t + 2 < 12) stage(0, t + 2);
        compute(1);
        __syncthreads();
    }

    u16* flat = (u16*)SHM;  // 131072 B = [256][256] u16
#pragma unroll
    for (int mf = 0; mf < 8; ++mf)
#pragma unroll
        for (int nf = 0; nf < 4; ++nf)
#pragma unroll
            for (int rg = 0; rg < 4; ++rg) {
                int row = wr * 128 + mf * 16 + (lane >> 4) * 4 + rg;
                int col = wc * 64 + nf * 16 + l15;
                flat[row * 256 + (col ^ ((row & 7) << 3))] = f2bf(acc[mf][nf][rg]);
            }
    __syncthreads();
    int row = tid >> 1;
    if (m0 + row < cnt) {
        int xr = (row & 7) << 3;
        int half = tid & 1;
        int pt = pairTok[base + m0 + row];
        u16* dst = C + (long)pt * K_ + n0 + half * 128;
#pragma unroll
        for (int jj = 0; jj < 16; ++jj) {
            *(u16x8*)(dst + jj * 8) =
                *(const u16x8*)&flat[row * 256 + ((half * 128 + jj * 8) ^ xr)];
        }
    }
}

// ---------------- combine ----------------
__global__ void k_combine(const u16* __restrict__ yb, const float* __restrict__ tw,
                          float* __restrict__ out) {
    long idx = ((long)blockIdx.x * 256 + threadIdx.x) * 8;
    int t = (int)(idx >> 11);
    float w0 = tw[t * 2 + 0];
    float w1 = tw[t * 2 + 1];
    u16x8 y0 = *(const u16x8*)(yb + (long)(2 * t) * K_ + (idx & (K_ - 1)));
    u16x8 y1 = *(const u16x8*)(yb + (long)(2 * t + 1) * K_ + (idx & (K_ - 1)));
    float4v o0, o1;
#pragma unroll
    for (int j = 0; j < 4; ++j) o0[j] = w0 * bf2f(y0[j]) + w1 * bf2f(y1[j]);
#pragma unroll
    for (int j = 0; j < 4; ++j) o1[j] = w0 * bf2f(y0[4 + j]) + w1 * bf2f(y1[4 + j]);
    *(float4v*)(out + idx) = o0;
    *(float4v*)(out + idx + 4) = o1;
}

// ---------------- launch ----------------
extern "C" void kernel_launch(void* const* d_in, const int* in_sizes, int n_in,
                              void* d_out, int out_size, void* d_ws, size_t ws_size,
                              hipStream_t stream) {
    const float* x       = (const float*)d_in[0];
    const float* logits  = (const float*)d_in[1];
    const int*   w13q    = (const int*)d_in[2];
    const int*   w2q     = (const int*)d_in[3];
    const float* alpha13 = (const float*)d_in[4];
    const float* alpha2  = (const float*)d_in[5];
    float* out = (float*)d_out;

    char* ws = (char*)d_ws;
    i8*  wc13 = (i8*)(ws);                          // 25165824 B (codes i8)
    u16* wb2  = (u16*)(ws + 50331648);              // 25165824 B (bf16, alpha2 folded)
    i8*  xq   = (i8*)(ws + 75497472);               // 16777216 B (pair-id order)
    u16* ab   = (u16*)(ws + 92274688);              // 12582912 B (silu*u bf16, list order)
    u16* yb   = (u16*)(ws + 104857600);             // 33554432 B
    int* pairTok = (int*)(ws + 138412032);          // 8192 ints
    int* tid2    = pairTok + NPAIR;                 // 8192 ints
    float* tw    = (float*)(tid2 + NPAIR);          // 8192 floats
    int* counts  = (int*)(tw + NPAIR);              // 8 (unused)
    int* offsets = counts + 8;                      // 9
    int* cursors = offsets + 9;                     // 8
    float* sx    = (float*)(cursors + 8);           // 8192 floats (pair-id order)

    // fused streaming: w13 conversion + routing + per-pair quantization
    k_fusedA<<<NBLK, 256, 0, stream>>>(
        w13q, logits, x, alpha13, wc13, xq, sx, tid2, tw, cursors);

    // histogram + offsets + per-expert token lists (single dispatch)
    k_lists2<<<T_ / 256, 256, 0, stream>>>(tid2, offsets, cursors, pairTok);

    // GEMM1 i8 + fused silu*u -> ab; extra blocks convert w2 -> wb2 concurrently
    k_g1i8<<<G1GRID + CVT2BLK, 512, 0, stream>>>(
        xq, wc13, pairTok, offsets, sx, ab, w2q, alpha2, wb2);

    // GEMM2 bf16 (M x 2048 x 768) -> yb scattered by pair
    k_g2<<<8 * (T_ / 256) * (K_ / 256), 512, 0, stream>>>(ab, wb2, pairTok, offsets, yb);

    // combine
    k_combine<<<((long)T_ * K_) / 8 / 256, 256, 0, stream>>>(yb, tw, out);
}

// Round 19
// 155.714 us; speedup vs baseline: 1.5002x; 1.2794x over previous
//
#include <hip/hip_runtime.h>
#include <math.h>

#define E_ 8
#define T_ 4096
#define K_ 2048
#define I_ 768
#define TWOI 1536
#define NPAIR (2*T_)

typedef unsigned short u16;
typedef signed char i8;
typedef unsigned char u8;
typedef __attribute__((ext_vector_type(8))) __bf16 bf16x8;
typedef __attribute__((ext_vector_type(4))) float f32x4;
typedef __attribute__((ext_vector_type(4))) int i32x4;
typedef __attribute__((ext_vector_type(8))) u16 u16x8;
typedef __attribute__((ext_vector_type(4))) u16 u16x4;
typedef __attribute__((ext_vector_type(4))) int int4v;
typedef __attribute__((ext_vector_type(4))) float float4v;

typedef __attribute__((address_space(3))) char lds_c;
typedef __attribute__((address_space(1))) const char g_c;

__device__ inline void gld16(const void* g, void* l) {
    __builtin_amdgcn_global_load_lds((g_c*)g, (lds_c*)l, 16, 0, 0);
}

__device__ inline u16 f2bf(float x) {
    unsigned u = __builtin_bit_cast(unsigned, x);
    unsigned r = 0x7fffu + ((u >> 16) & 1u);
    u += r;
    return (u16)(u >> 16);
}
__device__ inline float bf2f(u16 b) {
    unsigned u = ((unsigned)b) << 16;
    return __builtin_bit_cast(float, u);
}
__device__ inline unsigned pack4(int4v q) {
    return (unsigned)((unsigned char)(char)(q[0] - 1))
         | ((unsigned)((unsigned char)(char)(q[1] - 1)) << 8)
         | ((unsigned)((unsigned char)(char)(q[2] - 1)) << 16)
         | ((unsigned)((unsigned char)(char)(q[3] - 1)) << 24);
}

__device__ inline void route2(const float* l, int& e0, int& e1, float& mx0, float& mx1) {
    e0 = 0; mx0 = l[0];
#pragma unroll
    for (int e = 1; e < E_; ++e) if (l[e] > mx0) { mx0 = l[e]; e0 = e; }
    e1 = -1; mx1 = -1e30f;
#pragma unroll
    for (int e = 0; e < E_; ++e) if (e != e0 && l[e] > mx1) { mx1 = l[e]; e1 = e; }
}

// ---------------- front: lists (blocks 0..15) + streaming cvt13/cvt2/qx (blocks 16..2063) ----------------
#define NBLK 2048
#define LISTB 16
__global__ __launch_bounds__(256) void k_front(
    const int* __restrict__ w13q, const int* __restrict__ w2q,
    const float* __restrict__ alpha2, const float* __restrict__ logits,
    const float* __restrict__ x, const float* __restrict__ alpha13,
    i8* __restrict__ wc13, u16* __restrict__ wb2,
    i8* __restrict__ xq, float* __restrict__ sx,
    float* __restrict__ tw, int* __restrict__ offsets, int* __restrict__ pairTok)
{
    __shared__ u8 eArr[NPAIR];          // expert id per pair (lists blocks only)
    __shared__ int cmat[256][E_];
    __shared__ int offsS[E_ + 1];
    __shared__ int preS[E_];
    __shared__ int curS[E_];

    int tid = threadIdx.x;
    int bid = blockIdx.x;

    if (bid < LISTB) {
        int b = bid;
        // step 1: routing of ALL tokens (redundant per block); write tw for own range
#pragma unroll 1
        for (int it = 0; it < 16; ++it) {
            int t = tid + 256 * it;
            float l[E_];
#pragma unroll
            for (int e = 0; e < E_; ++e) l[e] = logits[t * E_ + e];
            int e0, e1; float mx0, mx1;
            route2(l, e0, e1, mx0, mx1);
            eArr[2 * t + 0] = (u8)e0;
            eArr[2 * t + 1] = (u8)e1;
            if ((t >> 8) == b) {
                float w0 = 1.0f / (1.0f + expf(mx1 - mx0));
                tw[2 * t + 0] = w0; tw[2 * t + 1] = 1.0f - w0;
            }
        }
        __syncthreads();
        // step 2: per-thread histogram over 32 pairs
        int c[E_];
#pragma unroll
        for (int e = 0; e < E_; ++e) c[e] = 0;
#pragma unroll 1
        for (int j = 0; j < 32; ++j) {
            int v = eArr[tid * 32 + j];
#pragma unroll
            for (int e = 0; e < E_; ++e) c[e] += (v == e) ? 1 : 0;
        }
#pragma unroll
        for (int e = 0; e < E_; ++e) cmat[tid][e] = c[e];
        __syncthreads();
        // totals + prefix (pairs from token-ranges before block b: threads j < b*16)
        if (tid < E_) {
            int e = tid;
            int tot = 0, pre = 0;
            int lim = b * 16;
            for (int j = 0; j < 256; ++j) {
                int v = cmat[j][e];
                tot += v;
                if (j < lim) pre += v;
            }
            cmat[0][e] = tot;   // reuse row 0 for totals
            preS[e] = pre;
            curS[e] = 0;
        }
        __syncthreads();
        if (tid == 0) {
            int s2 = 0;
            for (int e = 0; e < E_; ++e) { offsS[e] = s2; s2 += cmat[0][e]; }
            offsS[E_] = s2;
            if (b == 0)
                for (int e = 0; e <= E_; ++e) offsets[e] = offsS[e];
        }
        __syncthreads();
        // step 3: place own 256 tokens via block-local cursors (disjoint global slots)
        int t = b * 256 + tid;
#pragma unroll
        for (int s = 0; s < 2; ++s) {
            int e = eArr[2 * t + s];
            int pos = atomicAdd(&curS[e], 1);
            pairTok[offsS[e] + preS[e] + pos] = (t << 1) | s;
        }
        return;
    }

    int sid = bid - LISTB;   // 0..2047 streaming blocks
    // phase A: w13 int32 codes -> i8 (grid-stride, 12 iters, nt loads)
    {
        const int4v* src = (const int4v*)w13q;
        unsigned* dst = (unsigned*)wc13;
        const long n = 6291456;           // 25165824 / 4
        const long stride = (long)NBLK * 256;
#pragma unroll 2
        for (long u = (long)sid * 256 + tid; u < n; u += stride) {
            int4v q = __builtin_nontemporal_load(src + u);
            dst[u] = pack4(q);
        }
    }
    // phase B: w2 int32 codes -> bf16 * alpha2 (grid-stride, 6 iters)
    {
        const int4v* src = (const int4v*)w2q;
        const long n = 3145728;           // 12582912 / 4
        const long stride = (long)NBLK * 256;
#pragma unroll 2
        for (long u = (long)sid * 256 + tid; u < n; u += stride) {
            long g = u * 4;
            int i = (int)(g % I_);
            int e = (int)(g / ((long)K_ * I_));
            int4v q = __builtin_nontemporal_load(src + u);
            float4v a = *(const float4v*)(alpha2 + e * I_ + i);
            u16x4 r;
            r[0] = f2bf((float)(q[0] - 1) * a[0]);
            r[1] = f2bf((float)(q[1] - 1) * a[1]);
            r[2] = f2bf((float)(q[2] - 1) * a[2]);
            r[3] = f2bf((float)(q[3] - 1) * a[3]);
            *(u16x4*)(wb2 + g) = r;
        }
    }
    // phase C: wave-per-token routing + i8 quantization of BOTH pairs (x read once)
    {
        int wv = sid * 4 + (tid >> 6);
        if (wv < T_) {
            int lane = tid & 63;
            int t = wv;
            float l[E_];
#pragma unroll
            for (int e = 0; e < E_; ++e) l[e] = logits[t * E_ + e];
            int e0, e1; float mx0, mx1;
            route2(l, e0, e1, mx0, mx1);

            float4v xr[8];
#pragma unroll
            for (int c = 0; c < 8; ++c)
                xr[c] = *(const float4v*)(x + (long)t * K_ + c * 256 + lane * 4);

#pragma unroll
            for (int s = 0; s < 2; ++s) {
                int e = s ? e1 : e0;
                int p = 2 * t + s;
                float4v xa[8];
                float m = 0.f;
#pragma unroll
                for (int c = 0; c < 8; ++c) {
                    float4v a = *(const float4v*)(alpha13 + (long)e * K_ + c * 256 + lane * 4);
                    xa[c] = xr[c] * a;
#pragma unroll
                    for (int j = 0; j < 4; ++j) m = fmaxf(m, fabsf(xa[c][j]));
                }
#pragma unroll
                for (int off = 32; off >= 1; off >>= 1) m = fmaxf(m, __shfl_xor(m, off));
                float inv = (m > 0.f) ? 127.0f / m : 0.f;
#pragma unroll
                for (int c = 0; c < 8; ++c) {
                    unsigned pk = 0;
#pragma unroll
                    for (int j = 0; j < 4; ++j) {
                        int qv = __float2int_rn(xa[c][j] * inv);
                        pk |= ((unsigned)(unsigned char)(char)qv) << (8 * j);
                    }
                    *(unsigned*)(xq + (long)p * K_ + c * 256 + lane * 4) = pk;
                }
                if (lane == 0) sx[p] = m / 127.0f;
            }
        }
    }
}

// ---------------- GEMM1: i8 256x256 2-phase + fused silu*u (clean) ----------------
__global__ __launch_bounds__(512, 2) void k_g1i8(
    const i8* __restrict__ A,       // xq [NPAIR][K] pair-id order
    const i8* __restrict__ B,       // wc13 codes [E][2I][K]
    const int* __restrict__ pairTok, const int* __restrict__ offsets,
    const float* __restrict__ sx,   // [NPAIR] pair-id order
    u16* __restrict__ C)            // ab [NPAIR][I] list order = silu(g)*u
{
    int bid = blockIdx.x;
    int e  = bid & 7;
    int r_ = bid >> 3;
    int mc = r_ / 6;
    int nch = r_ % 6;
    int base = offsets[e];
    int cnt  = offsets[e + 1] - base;
    int m0 = mc * 256;
    if (m0 >= cnt) return;
    int n0 = nch * 128;

    __shared__ __attribute__((aligned(16))) i8 SHM[131072];
    i8* As = SHM;
    i8* Bs = SHM + 65536;

    int tid = threadIdx.x;
    int lane = tid & 63;
    int wid = tid >> 6;
    int wr = wid >> 2, wc = wid & 3;
    int l15 = lane & 15;

    const i8* srcA[4];
    const i8* srcB[4];
#pragma unroll
    for (int j = 0; j < 4; ++j) {
        int chunk = j * 512 + tid;
        int row = chunk >> 3, ch = chunk & 7;
        int colsw = (ch ^ (row & 7)) * 16;
        int ra = m0 + row; if (ra >= cnt) ra = cnt - 1;
        srcA[j] = A + (long)pairTok[base + ra] * K_ + colsw;
        int grow = e * TWOI + (row >> 7) * I_ + n0 + (row & 127);
        srcB[j] = B + (long)grow * K_ + colsw;
    }

    auto stage = [&](int bs, int t) {
        int k0 = t * 128;
        i8* dA = As + bs * 32768;
        i8* dB = Bs + bs * 32768;
#pragma unroll
        for (int j = 0; j < 4; ++j) {
            gld16(srcA[j] + k0, dA + j * 8192 + tid * 16);
            gld16(srcB[j] + k0, dB + j * 8192 + tid * 16);
        }
    };

    int kq16 = ((lane >> 4) & 3) * 16;

    i32x4 a[4][2], b[4][2];
    i32x4 acc[8][4];
#pragma unroll
    for (int mf = 0; mf < 8; ++mf)
#pragma unroll
        for (int nf = 0; nf < 4; ++nf)
            acc[mf][nf] = (i32x4){0, 0, 0, 0};

    auto rdA = [&](int bs, int h64) {
#pragma unroll
        for (int mf = 0; mf < 4; ++mf) {
            int row = wr * 128 + h64 + mf * 16 + l15;
            const i8* p = As + bs * 32768 + row * 128;
            int xr = (row & 7) << 4;
            a[mf][0] = *(const i32x4*)(p + ((kq16) ^ xr));
            a[mf][1] = *(const i32x4*)(p + ((64 + kq16) ^ xr));
        }
    };
    auto rdB = [&](int bs) {
#pragma unroll
        for (int nf = 0; nf < 4; ++nf) {
            int row = wc * 64 + nf * 16 + l15;
            const i8* p = Bs + bs * 32768 + row * 128;
            int xr = (row & 7) << 4;
            b[nf][0] = *(const i32x4*)(p + ((kq16) ^ xr));
            b[nf][1] = *(const i32x4*)(p + ((64 + kq16) ^ xr));
        }
    };
    auto mm = [&](int mh) {
#pragma unroll
        for (int ks = 0; ks < 2; ++ks)
#pragma unroll
            for (int mf = 0; mf < 4; ++mf)
#pragma unroll
                for (int nf = 0; nf < 4; ++nf)
                    acc[mh * 4 + mf][nf] = __builtin_amdgcn_mfma_i32_16x16x64_i8(
                        a[mf][ks], b[nf][ks], acc[mh * 4 + mf][nf], 0, 0, 0);
    };
    auto compute = [&](int bs) {
        rdB(bs);
        rdA(bs, 0);
        mm(0);
        rdA(bs, 64);
        mm(1);
    };

    stage(0, 0);
    __syncthreads();
#pragma unroll 1
    for (int t = 0; t < 16; t += 2) {
        stage(1, t + 1);
        compute(0);
        __syncthreads();
        if (t + 2 < 16) stage(0, t + 2);
        compute(1);
        __syncthreads();
    }

    u16* flat = (u16*)SHM;  // 131072 B = [256][256] u16
#pragma unroll
    for (int mf = 0; mf < 8; ++mf)
#pragma unroll
        for (int nf = 0; nf < 4; ++nf)
#pragma unroll
            for (int rg = 0; rg < 4; ++rg) {
                int row = wr * 128 + mf * 16 + (lane >> 4) * 4 + rg;
                int col = wc * 64 + nf * 16 + l15;
                flat[row * 256 + (col ^ ((row & 7) << 3))] = f2bf((float)acc[mf][nf][rg]);
            }
    __syncthreads();
    int row = tid >> 1;
    if (m0 + row < cnt) {
        float s = sx[pairTok[base + m0 + row]];
        int xr = (row & 7) << 3;
        int half = tid & 1;
        u16* dst = C + (long)(base + m0 + row) * I_ + n0 + half * 64;
#pragma unroll
        for (int jj = 0; jj < 8; ++jj) {
            u16x8 gv = *(const u16x8*)&flat[row * 256 + ((half * 64 + jj * 8) ^ xr)];
            u16x8 uv = *(const u16x8*)&flat[row * 256 + ((128 + half * 64 + jj * 8) ^ xr)];
            u16x8 r;
#pragma unroll
            for (int q = 0; q < 8; ++q) {
                float g = bf2f(gv[q]) * s, u = bf2f(uv[q]) * s;
                r[q] = f2bf(g / (1.0f + expf(-g)) * u);
            }
            *(u16x8*)(dst + jj * 8) = r;
        }
    }
}

// ---------------- GEMM2: bf16 256x256 2-phase -> yb ----------------
__global__ __launch_bounds__(512, 2) void k_g2(
    const u16* __restrict__ A,      // ab [NPAIR][I] bf16, list order
    const u16* __restrict__ B,      // wb2 [E][K][I] bf16 (alpha2 folded)
    const int* __restrict__ pairTok, const int* __restrict__ offsets,
    u16* __restrict__ C)            // yb [NPAIR][K] scattered by pair
{
    int bid = blockIdx.x;
    int e  = bid & 7;
    int r_ = bid >> 3;
    int mc = r_ >> 3;
    int nch = r_ & 7;
    int base = offsets[e];
    int cnt  = offsets[e + 1] - base;
    int m0 = mc * 256;
    if (m0 >= cnt) return;
    int n0 = nch * 256;

    __shared__ __attribute__((aligned(16))) char SHM[131072];
    u16* ldsA = (u16*)SHM;               // [2][256][64] u16 = 64 KB
    u16* ldsB = (u16*)(SHM + 65536);     // [2][256][64] u16 = 64 KB

    int tid = threadIdx.x;
    int lane = tid & 63;
    int wid = tid >> 6;
    int wr = wid >> 2, wc = wid & 3;
    int l15 = lane & 15;

    const u16* srcA[2][2];
    const u16* srcB[2][2];
#pragma unroll
    for (int h = 0; h < 2; ++h)
#pragma unroll
        for (int j = 0; j < 2; ++j) {
            int slot = j * 512 + tid;
            int row = slot >> 3, ch = slot & 7;
            int colsw = (ch ^ (row & 7)) * 8;
            int ra = m0 + h * 128 + row;
            if (ra >= cnt) ra = cnt - 1;
            srcA[h][j] = A + (long)(base + ra) * I_ + colsw;
            long brow = (long)e * K_ + n0 + h * 128 + row;
            srcB[h][j] = B + brow * (long)I_ + colsw;
        }
    int d0 = tid * 8, d1 = (512 + tid) * 8;

    auto stage = [&](int bs, int t) {
        int k0 = t * 64;
        u16* dA = ldsA + bs * 16384;
        u16* dB = ldsB + bs * 16384;
#pragma unroll
        for (int h = 0; h < 2; ++h) {
            gld16(srcA[h][0] + k0, dA + h * 8192 + d0);
            gld16(srcA[h][1] + k0, dA + h * 8192 + d1);
            gld16(srcB[h][0] + k0, dB + h * 8192 + d0);
            gld16(srcB[h][1] + k0, dB + h * 8192 + d1);
        }
    };

    int kc0 = ((((lane >> 4) & 3) * 8)) ^ ((lane & 7) * 8);
    int kc1 = (32 + (((lane >> 4) & 3) * 8)) ^ ((lane & 7) * 8);

    bf16x8 a[4][2], b[4][2];
    f32x4 acc[8][4];
#pragma unroll
    for (int mf = 0; mf < 8; ++mf)
#pragma unroll
        for (int nf = 0; nf < 4; ++nf)
            acc[mf][nf] = (f32x4){0.f, 0.f, 0.f, 0.f};

    auto rdA = [&](int bs, int h64) {
#pragma unroll
        for (int mf = 0; mf < 4; ++mf) {
            const u16* p = ldsA + bs * 16384 + (wr * 128 + h64 + mf * 16 + l15) * 64;
            a[mf][0] = __builtin_bit_cast(bf16x8, *(const u16x8*)(p + kc0));
            a[mf][1] = __builtin_bit_cast(bf16x8, *(const u16x8*)(p + kc1));
        }
    };
    auto rdB = [&](int bs) {
#pragma unroll
        for (int nf = 0; nf < 4; ++nf) {
            const u16* p = ldsB + bs * 16384 + (wc * 64 + nf * 16 + l15) * 64;
            b[nf][0] = __builtin_bit_cast(bf16x8, *(const u16x8*)(p + kc0));
            b[nf][1] = __builtin_bit_cast(bf16x8, *(const u16x8*)(p + kc1));
        }
    };
    auto mm = [&](int mh) {
#pragma unroll
        for (int ks = 0; ks < 2; ++ks)
#pragma unroll
            for (int mf = 0; mf < 4; ++mf)
#pragma unroll
                for (int nf = 0; nf < 4; ++nf)
                    acc[mh * 4 + mf][nf] = __builtin_amdgcn_mfma_f32_16x16x32_bf16(
                        a[mf][ks], b[nf][ks], acc[mh * 4 + mf][nf], 0, 0, 0);
    };
    auto compute = [&](int bs) {
        rdB(bs);
        rdA(bs, 0);
        mm(0);
        rdA(bs, 64);
        mm(1);
    };

    // NT = 12 (K-dim = I_ = 768, BK = 64)
    stage(0, 0);
    __syncthreads();
#pragma unroll 1
    for (int t = 0; t < 12; t += 2) {
        stage(1, t + 1);
        compute(0);
        __syncthreads();
        if (t + 2 < 12) stage(0, t + 2);
        compute(1);
        __syncthreads();
    }

    u16* flat = (u16*)SHM;  // 131072 B = [256][256] u16
#pragma unroll
    for (int mf = 0; mf < 8; ++mf)
#pragma unroll
        for (int nf = 0; nf < 4; ++nf)
#pragma unroll
            for (int rg = 0; rg < 4; ++rg) {
                int row = wr * 128 + mf * 16 + (lane >> 4) * 4 + rg;
                int col = wc * 64 + nf * 16 + l15;
                flat[row * 256 + (col ^ ((row & 7) << 3))] = f2bf(acc[mf][nf][rg]);
            }
    __syncthreads();
    int row = tid >> 1;
    if (m0 + row < cnt) {
        int xr = (row & 7) << 3;
        int half = tid & 1;
        int pt = pairTok[base + m0 + row];
        u16* dst = C + (long)pt * K_ + n0 + half * 128;
#pragma unroll
        for (int jj = 0; jj < 16; ++jj) {
            *(u16x8*)(dst + jj * 8) =
                *(const u16x8*)&flat[row * 256 + ((half * 128 + jj * 8) ^ xr)];
        }
    }
}

// ---------------- combine ----------------
__global__ void k_combine(const u16* __restrict__ yb, const float* __restrict__ tw,
                          float* __restrict__ out) {
    long idx = ((long)blockIdx.x * 256 + threadIdx.x) * 8;
    int t = (int)(idx >> 11);
    float w0 = tw[t * 2 + 0];
    float w1 = tw[t * 2 + 1];
    u16x8 y0 = *(const u16x8*)(yb + (long)(2 * t) * K_ + (idx & (K_ - 1)));
    u16x8 y1 = *(const u16x8*)(yb + (long)(2 * t + 1) * K_ + (idx & (K_ - 1)));
    float4v o0, o1;
#pragma unroll
    for (int j = 0; j < 4; ++j) o0[j] = w0 * bf2f(y0[j]) + w1 * bf2f(y1[j]);
#pragma unroll
    for (int j = 0; j < 4; ++j) o1[j] = w0 * bf2f(y0[4 + j]) + w1 * bf2f(y1[4 + j]);
    *(float4v*)(out + idx) = o0;
    *(float4v*)(out + idx + 4) = o1;
}

// ---------------- launch ----------------
extern "C" void kernel_launch(void* const* d_in, const int* in_sizes, int n_in,
                              void* d_out, int out_size, void* d_ws, size_t ws_size,
                              hipStream_t stream) {
    const float* x       = (const float*)d_in[0];
    const float* logits  = (const float*)d_in[1];
    const int*   w13q    = (const int*)d_in[2];
    const int*   w2q     = (const int*)d_in[3];
    const float* alpha13 = (const float*)d_in[4];
    const float* alpha2  = (const float*)d_in[5];
    float* out = (float*)d_out;

    char* ws = (char*)d_ws;
    i8*  wc13 = (i8*)(ws);                          // 25165824 B (codes i8)
    u16* wb2  = (u16*)(ws + 50331648);              // 25165824 B (bf16, alpha2 folded)
    i8*  xq   = (i8*)(ws + 75497472);               // 16777216 B (pair-id order)
    u16* ab   = (u16*)(ws + 92274688);              // 12582912 B (silu*u bf16, list order)
    u16* yb   = (u16*)(ws + 104857600);             // 33554432 B
    int* pairTok = (int*)(ws + 138412032);          // 8192 ints
    int* tid2    = pairTok + NPAIR;                 // (unused)
    float* tw    = (float*)(tid2 + NPAIR);          // 8192 floats
    int* counts  = (int*)(tw + NPAIR);              // (unused)
    int* offsets = counts + 8;                      // 9
    int* cursors = offsets + 9;                     // (unused)
    float* sx    = (float*)(cursors + 8);           // 8192 floats (pair-id order)

    // front: lists (16 blocks) + streaming cvt13/cvt2/qx (2048 blocks)
    k_front<<<LISTB + NBLK, 256, 0, stream>>>(
        w13q, w2q, alpha2, logits, x, alpha13, wc13, wb2, xq, sx, tw, offsets, pairTok);

    // GEMM1 i8 (M x [128g|128u] x 2048) + fused silu*u -> ab
    k_g1i8<<<8 * (T_ / 256) * 6, 512, 0, stream>>>(xq, wc13, pairTok, offsets, sx, ab);

    // GEMM2 bf16 (M x 2048 x 768) -> yb scattered by pair
    k_g2<<<8 * (T_ / 256) * (K_ / 256), 512, 0, stream>>>(ab, wb2, pairTok, offsets, yb);

    // combine
    k_combine<<<((long)T_ * K_) / 8 / 256, 256, 0, stream>>>(yb, tw, out);
}